// Round 6
// baseline (94.519 us; speedup 1.0000x reference)
//
#include <hip/hip_runtime.h>
#include <cstdint>
#include <cstddef>

typedef __bf16 bf16x8 __attribute__((ext_vector_type(8)));
typedef float f32x4 __attribute__((ext_vector_type(4)));

#define B_ 8
#define T_ 2048
#define C_ 1024
#define H_ 128

// C^-0.5 * log2(e): folded into Q at projection; softmax runs in exp2-space.
#define QSC 0.045084220027780106f

__device__ __forceinline__ unsigned short f2bf(float f) {
    __bf16 h = (__bf16)f;
    return *(unsigned short*)&h;
}

// async global->LDS, 16B per lane. LDS dest must be the wave-uniform base;
// HW adds lane*16. Global src is per-lane.
__device__ __forceinline__ void gload16(void* lds, const void* g) {
    __builtin_amdgcn_global_load_lds(
        (const __attribute__((address_space(1))) unsigned int*)g,
        (__attribute__((address_space(3))) unsigned int*)lds, 16, 0, 0);
}

// ---------------------------------------------------------------------------
// prep_w: WT[which][n][k] bf16  <-  W[k][n] f32.
// ---------------------------------------------------------------------------
__global__ __launch_bounds__(256) void prep_w(
    const float* __restrict__ Wq, const float* __restrict__ Wk,
    const float* __restrict__ Wv, unsigned short* __restrict__ wt)
{
    int gid = blockIdx.x * 256 + threadIdx.x;        // 49152 total
    int which = gid >> 14;
    int rem = gid & 16383;
    int n = rem >> 7;            // 0..127
    int kc = rem & 127;          // k-chunk of 8
    const float* W = which == 0 ? Wq : (which == 1 ? Wk : Wv);
    unsigned short tmp[8];
    #pragma unroll
    for (int i = 0; i < 8; ++i) tmp[i] = f2bf(W[(size_t)(kc * 8 + i) * H_ + n]);
    *(uint4*)&wt[((size_t)which * H_ + n) * C_ + kc * 8] = *(uint4*)tmp;
}

// ---------------------------------------------------------------------------
// proj: out = x @ W + b in bf16 MFMA. BM=64, BN=128, BK=64, 4 waves (2Mx2N),
// double-buffered. Q output is pre-scaled by QSC. V stored transposed.
// ---------------------------------------------------------------------------
__global__ __launch_bounds__(256) void proj_kernel(
    const float* __restrict__ x, const unsigned short* __restrict__ wt,
    const float* __restrict__ bq, const float* __restrict__ bk,
    const float* __restrict__ bv,
    unsigned short* __restrict__ qo, unsigned short* __restrict__ ko,
    unsigned short* __restrict__ vo)
{
    const int which = blockIdx.y;
    const float* bias = which == 0 ? bq : (which == 1 ? bk : bv);

    __shared__ unsigned short xs[2][64 * 64];    // [m][k] bf16, chunk-XOR swizzled
    __shared__ unsigned short ws2[2][128 * 64];  // [n][k] bf16, chunk-XOR swizzled

    const int tid = threadIdx.x;
    const int w = tid >> 6, l = tid & 63, g = l >> 4, lc = l & 15;
    const int wm = w & 1, wn = w >> 1;
    const int m0 = blockIdx.x * 64;

    const int sr = tid >> 2;
    const int sc2 = (tid & 3) * 2;
    const float* xrow = &x[(size_t)(m0 + sr) * C_ + sc2 * 8];
    const int xst0 = (sr * 8 + (sc2 ^ (sr & 7))) * 8;
    const int xst1 = (sr * 8 + ((sc2 + 1) ^ (sr & 7))) * 8;

    const unsigned short* wbase = &wt[(size_t)which * H_ * C_];

    f32x4 acc[2][4];
    #pragma unroll
    for (int im = 0; im < 2; ++im)
        #pragma unroll
        for (int jn = 0; jn < 4; ++jn) acc[im][jn] = f32x4{0.f, 0.f, 0.f, 0.f};

    float xr[16];
    #pragma unroll
    for (int j = 0; j < 4; ++j) {
        int slot = w * 256 + j * 64 + l;
        int r = slot >> 3, cs = slot & 7;
        gload16(&ws2[0][(w * 256 + j * 64) * 8],
                &wbase[(size_t)r * C_ + ((cs ^ (r & 7)) * 8)]);
    }
    #pragma unroll
    for (int i = 0; i < 4; ++i) {
        float4 v4 = *(const float4*)(xrow + i * 4);
        xr[i * 4 + 0] = v4.x; xr[i * 4 + 1] = v4.y;
        xr[i * 4 + 2] = v4.z; xr[i * 4 + 3] = v4.w;
    }
    {
        unsigned short tb[16];
        #pragma unroll
        for (int i = 0; i < 16; ++i) tb[i] = f2bf(xr[i]);
        *(uint4*)&xs[0][xst0] = *(uint4*)&tb[0];
        *(uint4*)&xs[0][xst1] = *(uint4*)&tb[8];
    }
    __syncthreads();

    int cur = 0;
    for (int kc = 0; kc < 16; ++kc) {
        const int nxt = cur ^ 1;
        const int kb2 = (kc + 1) * 64;
        if (kc < 15) {
            #pragma unroll
            for (int j = 0; j < 4; ++j) {
                int slot = w * 256 + j * 64 + l;
                int r = slot >> 3, cs = slot & 7;
                gload16(&ws2[nxt][(w * 256 + j * 64) * 8],
                        &wbase[(size_t)r * C_ + kb2 + ((cs ^ (r & 7)) * 8)]);
            }
            #pragma unroll
            for (int i = 0; i < 4; ++i) {
                float4 v4 = *(const float4*)(xrow + kb2 + i * 4);
                xr[i * 4 + 0] = v4.x; xr[i * 4 + 1] = v4.y;
                xr[i * 4 + 2] = v4.z; xr[i * 4 + 3] = v4.w;
            }
        }
        #pragma unroll
        for (int ks = 0; ks < 2; ++ks) {
            bf16x8 a[2], b[4];
            #pragma unroll
            for (int im = 0; im < 2; ++im) {
                int row = wm * 32 + im * 16 + lc;
                a[im] = *(const bf16x8*)&xs[cur][(row * 8 + ((ks * 4 + g) ^ (row & 7))) * 8];
            }
            #pragma unroll
            for (int jn = 0; jn < 4; ++jn) {
                int n = wn * 64 + jn * 16 + lc;
                b[jn] = *(const bf16x8*)&ws2[cur][(n * 8 + ((ks * 4 + g) ^ (n & 7))) * 8];
            }
            #pragma unroll
            for (int im = 0; im < 2; ++im)
                #pragma unroll
                for (int jn = 0; jn < 4; ++jn)
                    acc[im][jn] = __builtin_amdgcn_mfma_f32_16x16x32_bf16(
                        a[im], b[jn], acc[im][jn], 0, 0, 0);
        }
        if (kc < 15) {
            unsigned short tb[16];
            #pragma unroll
            for (int i = 0; i < 16; ++i) tb[i] = f2bf(xr[i]);
            *(uint4*)&xs[nxt][xst0] = *(uint4*)&tb[0];
            *(uint4*)&xs[nxt][xst1] = *(uint4*)&tb[8];
        }
        __syncthreads();
        cur = nxt;
    }

    unsigned short* eb = &xs[0][0];   // 8192 elems, [64][128] or [128][64]
    if (which != 2) {
        const float osc = (which == 0) ? QSC : 1.0f;
        #pragma unroll
        for (int jn = 0; jn < 4; ++jn) {
            int n = wn * 64 + jn * 16 + lc;
            float bval = bias[n];
            #pragma unroll
            for (int im = 0; im < 2; ++im)
                #pragma unroll
                for (int r = 0; r < 4; ++r) {
                    int ml = wm * 32 + im * 16 + g * 4 + r;
                    eb[ml * 128 + n] = f2bf((acc[im][jn][r] + bval) * osc);
                }
        }
        __syncthreads();
        unsigned short* o = which == 0 ? qo : ko;
        #pragma unroll
        for (int i = 0; i < 4; ++i) {
            int cidx = i * 256 + tid;
            int row = cidx >> 4, c16 = cidx & 15;
            *(uint4*)&o[(size_t)(m0 + row) * H_ + c16 * 8] =
                *(const uint4*)&eb[row * 128 + c16 * 8];
        }
    } else {
        #pragma unroll
        for (int jn = 0; jn < 4; ++jn) {
            int n = wn * 64 + jn * 16 + lc;
            float bval = bias[n];
            #pragma unroll
            for (int im = 0; im < 2; ++im)
                #pragma unroll
                for (int r = 0; r < 4; ++r) {
                    int ml = wm * 32 + im * 16 + g * 4 + r;
                    eb[n * 64 + ml] = f2bf(acc[im][jn][r] + bval);
                }
        }
        __syncthreads();
        const int bi = m0 >> 11, t0 = m0 & (T_ - 1);
        #pragma unroll
        for (int i = 0; i < 4; ++i) {
            int cidx = i * 256 + tid;
            int n = cidx >> 3, cc = cidx & 7;
            *(uint4*)&vo[((size_t)(bi * H_ + n)) * T_ + t0 + cc * 8] =
                *(const uint4*)&eb[n * 64 + cc * 8];
        }
    }
}

// ---------------------------------------------------------------------------
// attn_split4: KV-split flash attention, XCD-pinned per batch.
// grid(8, 160): blockIdx.x = batch -> flattened id % 8 == batch -> each XCD
// serves ONE batch's K/V (2 MB, fits 4 MB L2). QBLK=32 (2 waves), KVBLK=32,
// chunks <=512 keys. K staged via gload16 dbuf; V loaded to regs EARLY
// (issue at iter top, consumed after softmax -> latency hidden, K prefetch
// stays in flight until barrier). No-max exp2 softmax, plain-sum partials.
// ---------------------------------------------------------------------------
__global__ __launch_bounds__(128, 4) void attn_split4(
    const unsigned short* __restrict__ q,
    const unsigned short* __restrict__ k,
    const unsigned short* __restrict__ vT,
    float* __restrict__ out,
    float* __restrict__ Ows, float* __restrict__ lws)
{
    const int bb = blockIdx.x;                 // batch -> XCD pin
    const int j = 159 - (int)blockIdx.y;
    int qt, c;
    if (j < 16)      { qt = j;                    c = 0; }
    else if (j < 48) { qt = 16 + ((j - 16) >> 1); c = (j - 16) & 1; }
    else if (j < 96) { qt = 32 + (j - 48) / 3;    c = (j - 48) % 3; }
    else             { qt = 48 + ((j - 96) >> 2); c = (j - 96) & 3; }
    const int q0 = qt * 32;
    const int kstart = c * 512;
    const int kend = min(kstart + 512, q0 + 32);
    const int ntiles = (kend - kstart) >> 5;   // KVBLK=32

    const unsigned short* qb = q  + (size_t)bb * T_ * H_;
    const unsigned short* kb = k  + (size_t)bb * T_ * H_;
    const unsigned short* vb = vT + (size_t)bb * H_ * T_;

    __shared__ unsigned short Ks[2][32 * 128];   // 16 KB, chunk-XOR swizzled
    __shared__ unsigned short Ps[2][16 * 64];    // 4 KB, per-wave

    const int tid = threadIdx.x;
    const int w = tid >> 6, l = tid & 63, gl = l >> 4, lc = l & 15;

    bf16x8 aq[4];
    #pragma unroll
    for (int ds = 0; ds < 4; ++ds)
        aq[ds] = *(const bf16x8*)&qb[(size_t)(q0 + w * 16 + lc) * H_ + ds * 32 + gl * 8];

    f32x4 o[8];
    #pragma unroll
    for (int jo = 0; jo < 8; ++jo) o[jo] = f32x4{0.f, 0.f, 0.f, 0.f};
    float l_acc[4];
    #pragma unroll
    for (int r = 0; r < 4; ++r) l_acc[r] = 0.f;

    auto stageK = [&](int buf, int t) {
        const int kv0 = kstart + t * 32;
        #pragma unroll
        for (int jj = 0; jj < 4; ++jj) {
            int slot = (w * 4 + jj) * 64 + l;          // 0..511 (16B units)
            int r = slot >> 4, cs = slot & 15;
            gload16(&Ks[buf][((w * 4 + jj) * 64) * 8],
                    &kb[(size_t)(kv0 + r) * H_ + ((cs ^ (r & 7)) * 8)]);
        }
    };

    stageK(0, 0);
    __syncthreads();

    int cur = 0;
    for (int t = 0; t < ntiles; ++t) {
        const int kv0 = kstart + t * 32;

        // V fragments for THIS tile: issue loads first (hidden under QK+softmax)
        bf16x8 vf[8];
        #pragma unroll
        for (int jo = 0; jo < 8; ++jo)
            vf[jo] = *(const bf16x8*)&vb[(size_t)(jo * 16 + lc) * T_ + kv0 + gl * 8];

        // prefetch next K tile (stays in flight until barrier)
        if (t + 1 < ntiles) stageK(cur ^ 1, t + 1);

        // S = Q K^T from LDS
        f32x4 s[2];
        #pragma unroll
        for (int jk = 0; jk < 2; ++jk) s[jk] = f32x4{0.f, 0.f, 0.f, 0.f};
        #pragma unroll
        for (int ds = 0; ds < 4; ++ds) {
            #pragma unroll
            for (int jk = 0; jk < 2; ++jk) {
                int row = jk * 16 + lc;
                bf16x8 kf = *(const bf16x8*)&Ks[cur][(row * 16 + ((ds * 4 + gl) ^ (row & 7))) * 8];
                s[jk] = __builtin_amdgcn_mfma_f32_16x16x32_bf16(aq[ds], kf, s[jk], 0, 0, 0);
            }
        }
        // causal mask: only the diagonal tile (last tile of last chunk)
        if (kv0 == q0) {
            #pragma unroll
            for (int jk = 0; jk < 2; ++jk)
                #pragma unroll
                for (int r = 0; r < 4; ++r)
                    if (jk * 16 + lc > w * 16 + gl * 4 + r) s[jk][r] = -1e30f;
        }
        // p = exp2(s); l lane-partials (no max tracking, no rescale)
        #pragma unroll
        for (int jk = 0; jk < 2; ++jk)
            #pragma unroll
            for (int r = 0; r < 4; ++r) {
                float p = exp2f(fminf(s[jk][r], 80.f));
                s[jk][r] = p;
                l_acc[r] += p;
            }
        // P -> per-wave LDS (same-wave RAW, no barrier needed)
        #pragma unroll
        for (int jk = 0; jk < 2; ++jk)
            #pragma unroll
            for (int r = 0; r < 4; ++r) {
                int row = gl * 4 + r;
                Ps[w][(row * 64 + jk * 16 + lc) ^ ((row & 7) << 3)] = f2bf(s[jk][r]);
            }
        // O += P @ V with the pre-issued V registers
        {
            bf16x8 pa = *(const bf16x8*)&Ps[w][(lc * 64 + gl * 8) ^ ((lc & 7) << 3)];
            #pragma unroll
            for (int jo = 0; jo < 8; ++jo)
                o[jo] = __builtin_amdgcn_mfma_f32_16x16x32_bf16(pa, vf[jo], o[jo], 0, 0, 0);
        }
        __syncthreads();
        cur ^= 1;
    }

    // reduce l over the 16 key-lanes (once per job)
    #pragma unroll
    for (int off = 1; off < 16; off <<= 1)
        #pragma unroll
        for (int r = 0; r < 4; ++r)
            l_acc[r] += __shfl_xor(l_acc[r], off, 64);

    if (j < 16) {
        // single-chunk job: write normalized output directly
        float* ob = out + (size_t)bb * T_ * H_;
        float inv[4];
        #pragma unroll
        for (int r = 0; r < 4; ++r) inv[r] = 1.0f / l_acc[r];
        #pragma unroll
        for (int jo = 0; jo < 8; ++jo)
            #pragma unroll
            for (int r = 0; r < 4; ++r)
                ob[(size_t)(q0 + w * 16 + gl * 4 + r) * H_ + jo * 16 + lc] = o[jo][r] * inv[r];
    } else {
        const int ps = bb * 144 + (j - 16);
        float* op = Ows + (size_t)ps * (32 * 128);
        #pragma unroll
        for (int jo = 0; jo < 8; ++jo)
            #pragma unroll
            for (int r = 0; r < 4; ++r)
                op[(w * 16 + gl * 4 + r) * 128 + jo * 16 + lc] = o[jo][r];
        if (lc == 0) {
            #pragma unroll
            for (int r = 0; r < 4; ++r)
                lws[ps * 32 + w * 16 + gl * 4 + r] = l_acc[r];
        }
    }
}

// ---------------------------------------------------------------------------
// combine: out[t] = sum_c O_c[t] / sum_c l_c[t] for t >= 512 (plain sums).
// 4 rows/block, 64 lanes/row (float2 each).
// ---------------------------------------------------------------------------
__global__ __launch_bounds__(256) void combine_kernel(
    const float* __restrict__ Ows, const float* __restrict__ lws,
    float* __restrict__ out)
{
    const int rowid = blockIdx.x * 4 + (threadIdx.x >> 6);   // 0..12287
    const int lane = threadIdx.x & 63;
    const int bb = rowid / 1536;
    const int t = 512 + (rowid - bb * 1536);
    const int qt = t >> 5;                                    // 16..63
    const int grp = qt >> 4;                                  // 1..3
    const int nch = grp + 1;
    const int j0 = (grp == 1) ? 16 + (qt - 16) * 2
                 : (grp == 2) ? 48 + (qt - 32) * 3
                              : 96 + (qt - 48) * 4;
    const int r32 = t & 31;
    const int base = bb * 144 + (j0 - 16);

    float L = 0.f;
    float2 acc = make_float2(0.f, 0.f);
    #pragma unroll
    for (int c = 0; c < 4; ++c)
        if (c < nch) {
            L += lws[(base + c) * 32 + r32];
            float2 ov = *(const float2*)&Ows[(size_t)(base + c) * (32 * 128) + r32 * 128 + lane * 2];
            acc.x += ov.x; acc.y += ov.y;
        }
    const float invL = 1.0f / L;
    float2 res = make_float2(acc.x * invL, acc.y * invL);
    *(float2*)&out[((size_t)bb * T_ + t) * H_ + lane * 2] = res;
}

// ---------------------------------------------------------------------------
// Fallback monolithic attention (only if ws too small). Max-tracking version.
// ---------------------------------------------------------------------------
__global__ __launch_bounds__(128) void attn_mono(
    const unsigned short* __restrict__ q,
    const unsigned short* __restrict__ k,
    const unsigned short* __restrict__ vT,
    float* __restrict__ out)
{
    const int qt = (gridDim.x - 1) - blockIdx.x;
    const int bb = blockIdx.y;
    const int q0 = qt * 32;
    const unsigned short* qb = q  + (size_t)bb * T_ * H_;
    const unsigned short* kb = k  + (size_t)bb * T_ * H_;
    const unsigned short* vb = vT + (size_t)bb * H_ * T_;

    __shared__ unsigned short Ps[2][16 * 64];

    const int tid = threadIdx.x;
    const int w = tid >> 6, l = tid & 63, gl = l >> 4, lc = l & 15;

    bf16x8 aq[4];
    #pragma unroll
    for (int ds = 0; ds < 4; ++ds)
        aq[ds] = *(const bf16x8*)&qb[(size_t)(q0 + w * 16 + lc) * H_ + ds * 32 + gl * 8];

    f32x4 o[8];
    #pragma unroll
    for (int jo = 0; jo < 8; ++jo) o[jo] = f32x4{0.f, 0.f, 0.f, 0.f};
    float m_run[4], l_run[4];
    #pragma unroll
    for (int r = 0; r < 4; ++r) { m_run[r] = -INFINITY; l_run[r] = 0.f; }

    const int nt = (q0 >> 6) + 1;
    for (int t = 0; t < nt; ++t) {
        const int kv0 = t * 64;
        f32x4 s[4];
        #pragma unroll
        for (int jk = 0; jk < 4; ++jk) s[jk] = f32x4{0.f, 0.f, 0.f, 0.f};
        #pragma unroll
        for (int ds = 0; ds < 4; ++ds)
            #pragma unroll
            for (int jk = 0; jk < 4; ++jk) {
                bf16x8 bf = *(const bf16x8*)&kb[(size_t)(kv0 + jk * 16 + lc) * H_ + ds * 32 + gl * 8];
                s[jk] = __builtin_amdgcn_mfma_f32_16x16x32_bf16(aq[ds], bf, s[jk], 0, 0, 0);
            }
        if (kv0 + 63 > q0) {
            const int rowg = q0 + w * 16 + gl * 4;
            #pragma unroll
            for (int jk = 0; jk < 4; ++jk)
                #pragma unroll
                for (int r = 0; r < 4; ++r)
                    if (kv0 + jk * 16 + lc > rowg + r) s[jk][r] = -1e30f;
        }
        float pm[4];
        #pragma unroll
        for (int r = 0; r < 4; ++r)
            pm[r] = fmaxf(fmaxf(s[0][r], s[1][r]), fmaxf(s[2][r], s[3][r]));
        #pragma unroll
        for (int off = 1; off < 16; off <<= 1)
            #pragma unroll
            for (int r = 0; r < 4; ++r)
                pm[r] = fmaxf(pm[r], __shfl_xor(pm[r], off, 64));
        float scl[4], rs[4];
        #pragma unroll
        for (int r = 0; r < 4; ++r) {
            float mn = fmaxf(m_run[r], pm[r]);
            scl[r] = exp2f(m_run[r] - mn);
            m_run[r] = mn;
            rs[r] = 0.f;
        }
        #pragma unroll
        for (int jk = 0; jk < 4; ++jk)
            #pragma unroll
            for (int r = 0; r < 4; ++r) {
                float p = exp2f(s[jk][r] - m_run[r]);
                s[jk][r] = p;
                rs[r] += p;
            }
        #pragma unroll
        for (int off = 1; off < 16; off <<= 1)
            #pragma unroll
            for (int r = 0; r < 4; ++r)
                rs[r] += __shfl_xor(rs[r], off, 64);
        #pragma unroll
        for (int r = 0; r < 4; ++r)
            l_run[r] = l_run[r] * scl[r] + rs[r];
        #pragma unroll
        for (int jo = 0; jo < 8; ++jo)
            #pragma unroll
            for (int r = 0; r < 4; ++r)
                o[jo][r] *= scl[r];
        #pragma unroll
        for (int jk = 0; jk < 4; ++jk)
            #pragma unroll
            for (int r = 0; r < 4; ++r) {
                int row = gl * 4 + r;
                Ps[w][(row * 64 + jk * 16 + lc) ^ ((row & 7) << 3)] = f2bf(s[jk][r]);
            }
        #pragma unroll
        for (int ks = 0; ks < 2; ++ks) {
            bf16x8 pa = *(const bf16x8*)&Ps[w][(lc * 64 + ks * 32 + gl * 8) ^ ((lc & 7) << 3)];
            #pragma unroll
            for (int jo = 0; jo < 8; ++jo) {
                bf16x8 bv_ = *(const bf16x8*)&vb[(size_t)(jo * 16 + lc) * T_ + kv0 + ks * 32 + gl * 8];
                o[jo] = __builtin_amdgcn_mfma_f32_16x16x32_bf16(pa, bv_, o[jo], 0, 0, 0);
            }
        }
    }
    float* ob = out + (size_t)bb * T_ * H_;
    #pragma unroll
    for (int jo = 0; jo < 8; ++jo)
        #pragma unroll
        for (int r = 0; r < 4; ++r)
            ob[(size_t)(q0 + w * 16 + gl * 4 + r) * H_ + jo * 16 + lc] = o[jo][r] / l_run[r];
}

extern "C" void kernel_launch(void* const* d_in, const int* in_sizes, int n_in,
                              void* d_out, int out_size, void* d_ws, size_t ws_size,
                              hipStream_t stream) {
    const float* x  = (const float*)d_in[0];
    const float* Wq = (const float*)d_in[1];
    const float* bq = (const float*)d_in[2];
    const float* Wk = (const float*)d_in[3];
    const float* bk = (const float*)d_in[4];
    const float* Wv = (const float*)d_in[5];
    const float* bv = (const float*)d_in[6];
    float* out = (float*)d_out;

    const size_t qkv = (size_t)B_ * T_ * H_;               // 2M elems
    unsigned short* qws = (unsigned short*)d_ws;
    unsigned short* kws = qws + qkv;
    unsigned short* vws = kws + qkv;                       // [B,H,T] transposed
    unsigned short* wtw = vws + qkv;                       // [3,H,C]
    const size_t base_bytes = (3 * qkv + (size_t)3 * H_ * C_) * 2;  // 13,369,344
    float* Ows = (float*)((char*)d_ws + base_bytes);       // 1152 slots x 32x128 f32
    float* lws = Ows + (size_t)1152 * 32 * 128;            // 1152 x 32 f32
    const size_t need = base_bytes + ((size_t)1152 * 32 * 128 + 1152 * 32) * 4;

    prep_w<<<dim3(192), 256, 0, stream>>>(Wq, Wk, Wv, wtw);
    proj_kernel<<<dim3(256, 3), 256, 0, stream>>>(x, wtw, bq, bk, bv, qws, kws, vws);
    if (ws_size >= need) {
        attn_split4<<<dim3(8, 160), 128, 0, stream>>>(qws, kws, vws, out, Ows, lws);
        combine_kernel<<<dim3(3072), 256, 0, stream>>>(Ows, lws, out);
    } else {
        attn_mono<<<dim3(64, 8), 128, 0, stream>>>(qws, kws, vws, out);
    }
}

// Round 7
// 79.317 us; speedup vs baseline: 1.1917x; 1.1917x over previous
//
#include <hip/hip_runtime.h>
#include <cstdint>
#include <cstddef>

typedef __bf16 bf16x8 __attribute__((ext_vector_type(8)));
typedef float f32x4 __attribute__((ext_vector_type(4)));

#define B_ 8
#define T_ 2048
#define C_ 1024
#define H_ 128

// C^-0.5 * log2(e): folded into Q at projection; softmax runs in exp2-space.
#define QSC 0.045084220027780106f

__device__ __forceinline__ unsigned short f2bf(float f) {
    __bf16 h = (__bf16)f;
    return *(unsigned short*)&h;
}

// async global->LDS, 16B per lane. LDS dest must be the wave-uniform base;
// HW adds lane*16. Global src is per-lane.
__device__ __forceinline__ void gload16(void* lds, const void* g) {
    __builtin_amdgcn_global_load_lds(
        (const __attribute__((address_space(1))) unsigned int*)g,
        (__attribute__((address_space(3))) unsigned int*)lds, 16, 0, 0);
}

// ---------------------------------------------------------------------------
// prep_w: WT[which][n][k] bf16  <-  W[k][n] f32.
// ---------------------------------------------------------------------------
__global__ __launch_bounds__(256) void prep_w(
    const float* __restrict__ Wq, const float* __restrict__ Wk,
    const float* __restrict__ Wv, unsigned short* __restrict__ wt)
{
    int gid = blockIdx.x * 256 + threadIdx.x;        // 49152 total
    int which = gid >> 14;
    int rem = gid & 16383;
    int n = rem >> 7;            // 0..127
    int kc = rem & 127;          // k-chunk of 8
    const float* W = which == 0 ? Wq : (which == 1 ? Wk : Wv);
    unsigned short tmp[8];
    #pragma unroll
    for (int i = 0; i < 8; ++i) tmp[i] = f2bf(W[(size_t)(kc * 8 + i) * H_ + n]);
    *(uint4*)&wt[((size_t)which * H_ + n) * C_ + kc * 8] = *(uint4*)tmp;
}

// ---------------------------------------------------------------------------
// proj: out = x @ W + b in bf16 MFMA. BM=64, BN=128, BK=64, 4 waves (2Mx2N),
// double-buffered. Q output is pre-scaled by QSC. V stored transposed.
// ---------------------------------------------------------------------------
__global__ __launch_bounds__(256) void proj_kernel(
    const float* __restrict__ x, const unsigned short* __restrict__ wt,
    const float* __restrict__ bq, const float* __restrict__ bk,
    const float* __restrict__ bv,
    unsigned short* __restrict__ qo, unsigned short* __restrict__ ko,
    unsigned short* __restrict__ vo)
{
    const int which = blockIdx.y;
    const float* bias = which == 0 ? bq : (which == 1 ? bk : bv);

    __shared__ unsigned short xs[2][64 * 64];    // [m][k] bf16, chunk-XOR swizzled
    __shared__ unsigned short ws2[2][128 * 64];  // [n][k] bf16, chunk-XOR swizzled

    const int tid = threadIdx.x;
    const int w = tid >> 6, l = tid & 63, g = l >> 4, lc = l & 15;
    const int wm = w & 1, wn = w >> 1;
    const int m0 = blockIdx.x * 64;

    const int sr = tid >> 2;
    const int sc2 = (tid & 3) * 2;
    const float* xrow = &x[(size_t)(m0 + sr) * C_ + sc2 * 8];
    const int xst0 = (sr * 8 + (sc2 ^ (sr & 7))) * 8;
    const int xst1 = (sr * 8 + ((sc2 + 1) ^ (sr & 7))) * 8;

    const unsigned short* wbase = &wt[(size_t)which * H_ * C_];

    f32x4 acc[2][4];
    #pragma unroll
    for (int im = 0; im < 2; ++im)
        #pragma unroll
        for (int jn = 0; jn < 4; ++jn) acc[im][jn] = f32x4{0.f, 0.f, 0.f, 0.f};

    float xr[16];
    #pragma unroll
    for (int j = 0; j < 4; ++j) {
        int slot = w * 256 + j * 64 + l;
        int r = slot >> 3, cs = slot & 7;
        gload16(&ws2[0][(w * 256 + j * 64) * 8],
                &wbase[(size_t)r * C_ + ((cs ^ (r & 7)) * 8)]);
    }
    #pragma unroll
    for (int i = 0; i < 4; ++i) {
        float4 v4 = *(const float4*)(xrow + i * 4);
        xr[i * 4 + 0] = v4.x; xr[i * 4 + 1] = v4.y;
        xr[i * 4 + 2] = v4.z; xr[i * 4 + 3] = v4.w;
    }
    {
        unsigned short tb[16];
        #pragma unroll
        for (int i = 0; i < 16; ++i) tb[i] = f2bf(xr[i]);
        *(uint4*)&xs[0][xst0] = *(uint4*)&tb[0];
        *(uint4*)&xs[0][xst1] = *(uint4*)&tb[8];
    }
    __syncthreads();

    int cur = 0;
    for (int kc = 0; kc < 16; ++kc) {
        const int nxt = cur ^ 1;
        const int kb2 = (kc + 1) * 64;
        if (kc < 15) {
            #pragma unroll
            for (int j = 0; j < 4; ++j) {
                int slot = w * 256 + j * 64 + l;
                int r = slot >> 3, cs = slot & 7;
                gload16(&ws2[nxt][(w * 256 + j * 64) * 8],
                        &wbase[(size_t)r * C_ + kb2 + ((cs ^ (r & 7)) * 8)]);
            }
            #pragma unroll
            for (int i = 0; i < 4; ++i) {
                float4 v4 = *(const float4*)(xrow + kb2 + i * 4);
                xr[i * 4 + 0] = v4.x; xr[i * 4 + 1] = v4.y;
                xr[i * 4 + 2] = v4.z; xr[i * 4 + 3] = v4.w;
            }
        }
        #pragma unroll
        for (int ks = 0; ks < 2; ++ks) {
            bf16x8 a[2], b[4];
            #pragma unroll
            for (int im = 0; im < 2; ++im) {
                int row = wm * 32 + im * 16 + lc;
                a[im] = *(const bf16x8*)&xs[cur][(row * 8 + ((ks * 4 + g) ^ (row & 7))) * 8];
            }
            #pragma unroll
            for (int jn = 0; jn < 4; ++jn) {
                int n = wn * 64 + jn * 16 + lc;
                b[jn] = *(const bf16x8*)&ws2[cur][(n * 8 + ((ks * 4 + g) ^ (n & 7))) * 8];
            }
            #pragma unroll
            for (int im = 0; im < 2; ++im)
                #pragma unroll
                for (int jn = 0; jn < 4; ++jn)
                    acc[im][jn] = __builtin_amdgcn_mfma_f32_16x16x32_bf16(
                        a[im], b[jn], acc[im][jn], 0, 0, 0);
        }
        if (kc < 15) {
            unsigned short tb[16];
            #pragma unroll
            for (int i = 0; i < 16; ++i) tb[i] = f2bf(xr[i]);
            *(uint4*)&xs[nxt][xst0] = *(uint4*)&tb[0];
            *(uint4*)&xs[nxt][xst1] = *(uint4*)&tb[8];
        }
        __syncthreads();
        cur = nxt;
    }

    unsigned short* eb = &xs[0][0];   // 8192 elems, [64][128] or [128][64]
    if (which != 2) {
        const float osc = (which == 0) ? QSC : 1.0f;
        #pragma unroll
        for (int jn = 0; jn < 4; ++jn) {
            int n = wn * 64 + jn * 16 + lc;
            float bval = bias[n];
            #pragma unroll
            for (int im = 0; im < 2; ++im)
                #pragma unroll
                for (int r = 0; r < 4; ++r) {
                    int ml = wm * 32 + im * 16 + g * 4 + r;
                    eb[ml * 128 + n] = f2bf((acc[im][jn][r] + bval) * osc);
                }
        }
        __syncthreads();
        unsigned short* o = which == 0 ? qo : ko;
        #pragma unroll
        for (int i = 0; i < 4; ++i) {
            int cidx = i * 256 + tid;
            int row = cidx >> 4, c16 = cidx & 15;
            *(uint4*)&o[(size_t)(m0 + row) * H_ + c16 * 8] =
                *(const uint4*)&eb[row * 128 + c16 * 8];
        }
    } else {
        #pragma unroll
        for (int jn = 0; jn < 4; ++jn) {
            int n = wn * 64 + jn * 16 + lc;
            float bval = bias[n];
            #pragma unroll
            for (int im = 0; im < 2; ++im)
                #pragma unroll
                for (int r = 0; r < 4; ++r) {
                    int ml = wm * 32 + im * 16 + g * 4 + r;
                    eb[n * 64 + ml] = f2bf(acc[im][jn][r] + bval);
                }
        }
        __syncthreads();
        const int bi = m0 >> 11, t0 = m0 & (T_ - 1);
        #pragma unroll
        for (int i = 0; i < 4; ++i) {
            int cidx = i * 256 + tid;
            int n = cidx >> 3, cc = cidx & 7;
            *(uint4*)&vo[((size_t)(bi * H_ + n)) * T_ + t0 + cc * 8] =
                *(const uint4*)&eb[n * 64 + cc * 8];
        }
    }
}

// ---------------------------------------------------------------------------
// attn_split5: KV-split flash attention, XCD-pinned per batch, with BOTH
// K and V staged in LDS via fire-and-forget gload16 (double-buffered,
// prefetched one full tile ahead -> zero global latency in the per-tile
// chain, zero VGPR cost for staging). QBLK=32 (2 waves), KVBLK=32, chunks
// <=512 keys. No-max exp2 softmax; plain-sum partials.
// LDS: K 16KB + V 16KB + P 4KB = 36KB -> 4 blocks/CU.
// ---------------------------------------------------------------------------
__global__ __launch_bounds__(128, 2) void attn_split5(
    const unsigned short* __restrict__ q,
    const unsigned short* __restrict__ k,
    const unsigned short* __restrict__ vT,
    float* __restrict__ out,
    float* __restrict__ Ows, float* __restrict__ lws)
{
    const int bb = blockIdx.x;                 // batch -> XCD pin
    const int j = 159 - (int)blockIdx.y;       // longest jobs first
    int qt, c;
    if (j < 16)      { qt = j;                    c = 0; }
    else if (j < 48) { qt = 16 + ((j - 16) >> 1); c = (j - 16) & 1; }
    else if (j < 96) { qt = 32 + (j - 48) / 3;    c = (j - 48) % 3; }
    else             { qt = 48 + ((j - 96) >> 2); c = (j - 96) & 3; }
    const int q0 = qt * 32;
    const int kstart = c * 512;
    const int kend = min(kstart + 512, q0 + 32);
    const int ntiles = (kend - kstart) >> 5;   // KVBLK=32

    const unsigned short* qb = q  + (size_t)bb * T_ * H_;
    const unsigned short* kb = k  + (size_t)bb * T_ * H_;
    const unsigned short* vb = vT + (size_t)bb * H_ * T_;

    __shared__ unsigned short Ks[2][32 * 128];   // [key][d], chunk-XOR swizzled
    __shared__ unsigned short Vs[2][128 * 32];   // [d][key], chunk-XOR swizzled
    __shared__ unsigned short Ps[2][16 * 64];    // per-wave P

    const int tid = threadIdx.x;
    const int w = tid >> 6, l = tid & 63, gl = l >> 4, lc = l & 15;

    bf16x8 aq[4];
    #pragma unroll
    for (int ds = 0; ds < 4; ++ds)
        aq[ds] = *(const bf16x8*)&qb[(size_t)(q0 + w * 16 + lc) * H_ + ds * 32 + gl * 8];

    f32x4 o[8];
    #pragma unroll
    for (int jo = 0; jo < 8; ++jo) o[jo] = f32x4{0.f, 0.f, 0.f, 0.f};
    float l_acc[4];
    #pragma unroll
    for (int r = 0; r < 4; ++r) l_acc[r] = 0.f;

    // K tile: [32 keys][128 d], 16 chunks of 8 per row, swizzle cs^(r&7)
    auto stageK = [&](int buf, int t) {
        const int kv0 = kstart + t * 32;
        #pragma unroll
        for (int jj = 0; jj < 4; ++jj) {
            int slot = (w * 4 + jj) * 64 + l;          // 0..511 (16B units)
            int r = slot >> 4, cs = slot & 15;
            gload16(&Ks[buf][((w * 4 + jj) * 64) * 8],
                    &kb[(size_t)(kv0 + r) * H_ + ((cs ^ (r & 7)) * 8)]);
        }
    };
    // V tile: [128 d][32 keys], 4 chunks of 8 per row, swizzle cs^(r&3)
    auto stageV = [&](int buf, int t) {
        const int kv0 = kstart + t * 32;
        #pragma unroll
        for (int jj = 0; jj < 4; ++jj) {
            int slot = (w * 4 + jj) * 64 + l;          // 0..511 (16B units)
            int r = slot >> 2, cs = slot & 3;
            gload16(&Vs[buf][((w * 4 + jj) * 64) * 8],
                    &vb[(size_t)r * T_ + kv0 + ((cs ^ (r & 3)) * 8)]);
        }
    };

    stageK(0, 0);
    stageV(0, 0);
    __syncthreads();

    int cur = 0;
    for (int t = 0; t < ntiles; ++t) {
        // prefetch next K+V tile (fire-and-forget; completes by the barrier)
        if (t + 1 < ntiles) { stageK(cur ^ 1, t + 1); stageV(cur ^ 1, t + 1); }
        const int kv0 = kstart + t * 32;

        // S = Q K^T from LDS
        f32x4 s[2];
        #pragma unroll
        for (int jk = 0; jk < 2; ++jk) s[jk] = f32x4{0.f, 0.f, 0.f, 0.f};
        #pragma unroll
        for (int ds = 0; ds < 4; ++ds) {
            #pragma unroll
            for (int jk = 0; jk < 2; ++jk) {
                int row = jk * 16 + lc;
                bf16x8 kf = *(const bf16x8*)&Ks[cur][(row * 16 + ((ds * 4 + gl) ^ (row & 7))) * 8];
                s[jk] = __builtin_amdgcn_mfma_f32_16x16x32_bf16(aq[ds], kf, s[jk], 0, 0, 0);
            }
        }
        // causal mask: only the diagonal tile (last tile of last chunk)
        if (kv0 == q0) {
            #pragma unroll
            for (int jk = 0; jk < 2; ++jk)
                #pragma unroll
                for (int r = 0; r < 4; ++r)
                    if (jk * 16 + lc > w * 16 + gl * 4 + r) s[jk][r] = -1e30f;
        }
        // p = exp2(s); l lane-partials (no max tracking, no rescale)
        #pragma unroll
        for (int jk = 0; jk < 2; ++jk)
            #pragma unroll
            for (int r = 0; r < 4; ++r) {
                float p = exp2f(fminf(s[jk][r], 80.f));
                s[jk][r] = p;
                l_acc[r] += p;
            }
        // P -> per-wave LDS (same-wave RAW, no barrier needed)
        #pragma unroll
        for (int jk = 0; jk < 2; ++jk)
            #pragma unroll
            for (int r = 0; r < 4; ++r) {
                int row = gl * 4 + r;
                Ps[w][(row * 64 + jk * 16 + lc) ^ ((row & 7) << 3)] = f2bf(s[jk][r]);
            }
        // O += P @ V from LDS
        {
            bf16x8 pa = *(const bf16x8*)&Ps[w][(lc * 64 + gl * 8) ^ ((lc & 7) << 3)];
            #pragma unroll
            for (int jo = 0; jo < 8; ++jo) {
                int d = jo * 16 + lc;
                bf16x8 vf = *(const bf16x8*)&Vs[cur][(d * 4 + (gl ^ (d & 3))) * 8];
                o[jo] = __builtin_amdgcn_mfma_f32_16x16x32_bf16(pa, vf, o[jo], 0, 0, 0);
            }
        }
        __syncthreads();
        cur ^= 1;
    }

    // reduce l over the 16 key-lanes (once per job)
    #pragma unroll
    for (int off = 1; off < 16; off <<= 1)
        #pragma unroll
        for (int r = 0; r < 4; ++r)
            l_acc[r] += __shfl_xor(l_acc[r], off, 64);

    if (j < 16) {
        // single-chunk job: write normalized output directly
        float* ob = out + (size_t)bb * T_ * H_;
        float inv[4];
        #pragma unroll
        for (int r = 0; r < 4; ++r) inv[r] = 1.0f / l_acc[r];
        #pragma unroll
        for (int jo = 0; jo < 8; ++jo)
            #pragma unroll
            for (int r = 0; r < 4; ++r)
                ob[(size_t)(q0 + w * 16 + gl * 4 + r) * H_ + jo * 16 + lc] = o[jo][r] * inv[r];
    } else {
        const int ps = bb * 144 + (j - 16);
        float* op = Ows + (size_t)ps * (32 * 128);
        #pragma unroll
        for (int jo = 0; jo < 8; ++jo)
            #pragma unroll
            for (int r = 0; r < 4; ++r)
                op[(w * 16 + gl * 4 + r) * 128 + jo * 16 + lc] = o[jo][r];
        if (lc == 0) {
            #pragma unroll
            for (int r = 0; r < 4; ++r)
                lws[ps * 32 + w * 16 + gl * 4 + r] = l_acc[r];
        }
    }
}

// ---------------------------------------------------------------------------
// combine: out[t] = sum_c O_c[t] / sum_c l_c[t] for t >= 512 (plain sums).
// 4 rows/block, 64 lanes/row (float2 each).
// ---------------------------------------------------------------------------
__global__ __launch_bounds__(256) void combine_kernel(
    const float* __restrict__ Ows, const float* __restrict__ lws,
    float* __restrict__ out)
{
    const int rowid = blockIdx.x * 4 + (threadIdx.x >> 6);   // 0..12287
    const int lane = threadIdx.x & 63;
    const int bb = rowid / 1536;
    const int t = 512 + (rowid - bb * 1536);
    const int qt = t >> 5;                                    // 16..63
    const int grp = qt >> 4;                                  // 1..3
    const int nch = grp + 1;
    const int j0 = (grp == 1) ? 16 + (qt - 16) * 2
                 : (grp == 2) ? 48 + (qt - 32) * 3
                              : 96 + (qt - 48) * 4;
    const int r32 = t & 31;
    const int base = bb * 144 + (j0 - 16);

    float L = 0.f;
    float2 acc = make_float2(0.f, 0.f);
    #pragma unroll
    for (int c = 0; c < 4; ++c)
        if (c < nch) {
            L += lws[(base + c) * 32 + r32];
            float2 ov = *(const float2*)&Ows[(size_t)(base + c) * (32 * 128) + r32 * 128 + lane * 2];
            acc.x += ov.x; acc.y += ov.y;
        }
    const float invL = 1.0f / L;
    float2 res = make_float2(acc.x * invL, acc.y * invL);
    *(float2*)&out[((size_t)bb * T_ + t) * H_ + lane * 2] = res;
}

// ---------------------------------------------------------------------------
// Fallback monolithic attention (only if ws too small). Max-tracking version.
// ---------------------------------------------------------------------------
__global__ __launch_bounds__(128) void attn_mono(
    const unsigned short* __restrict__ q,
    const unsigned short* __restrict__ k,
    const unsigned short* __restrict__ vT,
    float* __restrict__ out)
{
    const int qt = (gridDim.x - 1) - blockIdx.x;
    const int bb = blockIdx.y;
    const int q0 = qt * 32;
    const unsigned short* qb = q  + (size_t)bb * T_ * H_;
    const unsigned short* kb = k  + (size_t)bb * T_ * H_;
    const unsigned short* vb = vT + (size_t)bb * H_ * T_;

    __shared__ unsigned short Ps[2][16 * 64];

    const int tid = threadIdx.x;
    const int w = tid >> 6, l = tid & 63, gl = l >> 4, lc = l & 15;

    bf16x8 aq[4];
    #pragma unroll
    for (int ds = 0; ds < 4; ++ds)
        aq[ds] = *(const bf16x8*)&qb[(size_t)(q0 + w * 16 + lc) * H_ + ds * 32 + gl * 8];

    f32x4 o[8];
    #pragma unroll
    for (int jo = 0; jo < 8; ++jo) o[jo] = f32x4{0.f, 0.f, 0.f, 0.f};
    float m_run[4], l_run[4];
    #pragma unroll
    for (int r = 0; r < 4; ++r) { m_run[r] = -INFINITY; l_run[r] = 0.f; }

    const int nt = (q0 >> 6) + 1;
    for (int t = 0; t < nt; ++t) {
        const int kv0 = t * 64;
        f32x4 s[4];
        #pragma unroll
        for (int jk = 0; jk < 4; ++jk) s[jk] = f32x4{0.f, 0.f, 0.f, 0.f};
        #pragma unroll
        for (int ds = 0; ds < 4; ++ds)
            #pragma unroll
            for (int jk = 0; jk < 4; ++jk) {
                bf16x8 bf = *(const bf16x8*)&kb[(size_t)(kv0 + jk * 16 + lc) * H_ + ds * 32 + gl * 8];
                s[jk] = __builtin_amdgcn_mfma_f32_16x16x32_bf16(aq[ds], bf, s[jk], 0, 0, 0);
            }
        if (kv0 + 63 > q0) {
            const int rowg = q0 + w * 16 + gl * 4;
            #pragma unroll
            for (int jk = 0; jk < 4; ++jk)
                #pragma unroll
                for (int r = 0; r < 4; ++r)
                    if (kv0 + jk * 16 + lc > rowg + r) s[jk][r] = -1e30f;
        }
        float pm[4];
        #pragma unroll
        for (int r = 0; r < 4; ++r)
            pm[r] = fmaxf(fmaxf(s[0][r], s[1][r]), fmaxf(s[2][r], s[3][r]));
        #pragma unroll
        for (int off = 1; off < 16; off <<= 1)
            #pragma unroll
            for (int r = 0; r < 4; ++r)
                pm[r] = fmaxf(pm[r], __shfl_xor(pm[r], off, 64));
        float scl[4], rs[4];
        #pragma unroll
        for (int r = 0; r < 4; ++r) {
            float mn = fmaxf(m_run[r], pm[r]);
            scl[r] = exp2f(m_run[r] - mn);
            m_run[r] = mn;
            rs[r] = 0.f;
        }
        #pragma unroll
        for (int jk = 0; jk < 4; ++jk)
            #pragma unroll
            for (int r = 0; r < 4; ++r) {
                float p = exp2f(s[jk][r] - m_run[r]);
                s[jk][r] = p;
                rs[r] += p;
            }
        #pragma unroll
        for (int off = 1; off < 16; off <<= 1)
            #pragma unroll
            for (int r = 0; r < 4; ++r)
                rs[r] += __shfl_xor(rs[r], off, 64);
        #pragma unroll
        for (int r = 0; r < 4; ++r)
            l_run[r] = l_run[r] * scl[r] + rs[r];
        #pragma unroll
        for (int jo = 0; jo < 8; ++jo)
            #pragma unroll
            for (int r = 0; r < 4; ++r)
                o[jo][r] *= scl[r];
        #pragma unroll
        for (int jk = 0; jk < 4; ++jk)
            #pragma unroll
            for (int r = 0; r < 4; ++r) {
                int row = gl * 4 + r;
                Ps[w][(row * 64 + jk * 16 + lc) ^ ((row & 7) << 3)] = f2bf(s[jk][r]);
            }
        #pragma unroll
        for (int ks = 0; ks < 2; ++ks) {
            bf16x8 pa = *(const bf16x8*)&Ps[w][(lc * 64 + ks * 32 + gl * 8) ^ ((lc & 7) << 3)];
            #pragma unroll
            for (int jo = 0; jo < 8; ++jo) {
                bf16x8 bv_ = *(const bf16x8*)&vb[(size_t)(jo * 16 + lc) * T_ + kv0 + ks * 32 + gl * 8];
                o[jo] = __builtin_amdgcn_mfma_f32_16x16x32_bf16(pa, bv_, o[jo], 0, 0, 0);
            }
        }
    }
    float* ob = out + (size_t)bb * T_ * H_;
    #pragma unroll
    for (int jo = 0; jo < 8; ++jo)
        #pragma unroll
        for (int r = 0; r < 4; ++r)
            ob[(size_t)(q0 + w * 16 + gl * 4 + r) * H_ + jo * 16 + lc] = o[jo][r] / l_run[r];
}

extern "C" void kernel_launch(void* const* d_in, const int* in_sizes, int n_in,
                              void* d_out, int out_size, void* d_ws, size_t ws_size,
                              hipStream_t stream) {
    const float* x  = (const float*)d_in[0];
    const float* Wq = (const float*)d_in[1];
    const float* bq = (const float*)d_in[2];
    const float* Wk = (const float*)d_in[3];
    const float* bk = (const float*)d_in[4];
    const float* Wv = (const float*)d_in[5];
    const float* bv = (const float*)d_in[6];
    float* out = (float*)d_out;

    const size_t qkv = (size_t)B_ * T_ * H_;               // 2M elems
    unsigned short* qws = (unsigned short*)d_ws;
    unsigned short* kws = qws + qkv;
    unsigned short* vws = kws + qkv;                       // [B,H,T] transposed
    unsigned short* wtw = vws + qkv;                       // [3,H,C]
    const size_t base_bytes = (3 * qkv + (size_t)3 * H_ * C_) * 2;  // 13,369,344
    float* Ows = (float*)((char*)d_ws + base_bytes);       // 1152 slots x 32x128 f32
    float* lws = Ows + (size_t)1152 * 32 * 128;            // 1152 x 32 f32
    const size_t need = base_bytes + ((size_t)1152 * 32 * 128 + 1152 * 32) * 4;

    prep_w<<<dim3(192), 256, 0, stream>>>(Wq, Wk, Wv, wtw);
    proj_kernel<<<dim3(256, 3), 256, 0, stream>>>(x, wtw, bq, bk, bv, qws, kws, vws);
    if (ws_size >= need) {
        attn_split5<<<dim3(8, 160), 128, 0, stream>>>(qws, kws, vws, out, Ows, lws);
        combine_kernel<<<dim3(3072), 256, 0, stream>>>(Ows, lws, out);
    } else {
        attn_mono<<<dim3(64, 8), 128, 0, stream>>>(qws, kws, vws, out);
    }
}